// Round 9
// baseline (824.366 us; speedup 1.0000x reference)
//
#include <hip/hip_runtime.h>
#include <cstdint>
#include <cstddef>

typedef __attribute__((ext_vector_type(8))) short short8;
typedef __attribute__((ext_vector_type(4))) short short4v;
typedef __attribute__((ext_vector_type(8))) __bf16 bf16x8;
typedef __attribute__((ext_vector_type(4))) float f32x4;
typedef unsigned short u16;

static constexpr int Bb = 32, Nn = 4096, NSs = 16, Dd = 512, Hh = 8, DFF = 2048;
static constexpr float SCALE = 0.125f;   // (64)^-0.5
static constexpr float EPSR  = 1e-8f;
static constexpr float LN_EPS = 1e-5f;

__device__ __forceinline__ u16 f2b(float x) {
  union { float f; uint32_t u; } a; a.f = x;
  uint32_t r = a.u + 0x7fffu + ((a.u >> 16) & 1u);
  return (u16)(r >> 16);
}

__device__ __forceinline__ f32x4 mfma16(short8 a, short8 b, f32x4 c) {
  return __builtin_amdgcn_mfma_f32_16x16x32_bf16(
      __builtin_bit_cast(bf16x8, a), __builtin_bit_cast(bf16x8, b), c, 0, 0, 0);
}

// async global->LDS, 16B per lane; LDS dest must be wave-uniform base (+lane*16 HW)
__device__ __forceinline__ void gload16(const u16* g, u16* l) {
  __builtin_amdgcn_global_load_lds(
      (const __attribute__((address_space(1))) void*)g,
      (__attribute__((address_space(3))) void*)l, 16, 0, 0);
}

// ---------------- LayerNorm rows: fp32 [R,512] -> bf16 [R,512] ----------------
__global__ __launch_bounds__(256) void ln_rows(const float* __restrict__ src,
    const float* __restrict__ g, const float* __restrict__ bt,
    u16* __restrict__ dst, int R) {
  int row = blockIdx.x * 4 + (threadIdx.x >> 6);
  if (row >= R) return;
  int lane = threadIdx.x & 63;
  const float* p = src + (size_t)row * Dd + lane * 8;
  float4 u0 = *(const float4*)p;
  float4 u1 = *(const float4*)(p + 4);
  float x[8] = {u0.x,u0.y,u0.z,u0.w,u1.x,u1.y,u1.z,u1.w};
  float s = 0.f, s2 = 0.f;
#pragma unroll
  for (int e = 0; e < 8; ++e) { s += x[e]; s2 += x[e]*x[e]; }
#pragma unroll
  for (int m = 1; m < 64; m <<= 1) { s += __shfl_xor(s, m); s2 += __shfl_xor(s2, m); }
  float mean = s * (1.f/512.f);
  float var  = s2 * (1.f/512.f) - mean*mean;
  float rstd = rsqrtf(var + LN_EPS);
  union { u16 o[8]; short8 v; } ou;
#pragma unroll
  for (int e = 0; e < 8; ++e)
    ou.o[e] = f2b((x[e]-mean)*rstd*g[lane*8+e] + bt[lane*8+e]);
  *(short8*)(dst + (size_t)row * Dd + lane * 8) = ou.v;
}

// ---------------- fused K/V GEMM 128x128: A in LDS, WEIGHTS FROM GLOBAL ------
// Wk/Wv are 512 KB each -> L2-resident. K/V fragments are loaded straight
// from global into registers (barrier-free, compiler-pipelined; each wave
// load = 16 fully-used 64B lines). Only A (xn) goes through LDS: BK=64
// single-buffer, 4 gload16/thread + 8 ds_read/wave per K-tile -- 3x less
// barrier-coupled staging than the all-LDS variants (R1-R8, all ~227us).
// LDS swizzle (R6, measured 0 conflicts): LDS[r][s] = G[r][s^(r&7)] via
// pre-swizzled global source; read slot (ks*4+lk)^(li&7).
__global__ __launch_bounds__(256, 2) void gemm_kv(const u16* __restrict__ A,
    const u16* __restrict__ Bk, const u16* __restrict__ Bv,
    u16* __restrict__ Ck, u16* __restrict__ CvT) {
  __shared__ u16 lA[128*64];   // 16 KB, single buffer
  const int tid = threadIdx.x, lane = tid & 63, wid = tid >> 6;
  const int wr = wid >> 1, wc = wid & 1;
  // bijective XCD swizzle: nwg=4096, 8 XCDs, 512 per XCD
  const int n  = blockIdx.x;
  const int orig = (n & 7) * 512 + (n >> 3);
  const int bm = (orig >> 2) * 128, bn = (orig & 3) * 128;
  const size_t BN = (size_t)Bb * Nn;
  f32x4 ak[4][4] = {};
  f32x4 av[4][4] = {};
  const int li = lane & 15, lk = lane >> 4;
  // staging: pass p covers rows p*32 + (tid>>3), 16B slot tid&7, row-XOR swz
  const int sr0 = tid >> 3, ss0 = tid & 7;
  // weight row bases for this wave's column half (frag rows indexed nn*16+li)
  const u16* Kp = Bk + (size_t)(bn + wc*64 + li) * Dd + lk*8;
  const u16* Vp = Bv + (size_t)(bn + wc*64 + li) * Dd + lk*8;
  for (int t = 0; t < 8; ++t) {
    const int k0 = t * 64;
    __syncthreads();                       // prev compute done
#pragma unroll
    for (int p = 0; p < 4; ++p) {
      const int rr = p*32 + sr0;
      gload16(A + (size_t)(bm + rr) * Dd + k0 + ((ss0 ^ (rr & 7)) * 8),
              &lA[(p*32 + wid*8) * 64]);
    }
    __syncthreads();                       // drains vmcnt(0): A tile ready
#pragma unroll
    for (int ks = 0; ks < 2; ++ks) {
      const int kc = k0 + ks*32;
      short8 af[4], kf[4], vf[4];
#pragma unroll
      for (int m = 0; m < 4; ++m)
        af[m] = *(const short8*)&lA[(wr*64 + m*16 + li)*64
                                    + (((ks*4 + lk) ^ (li & 7)) * 8)];
#pragma unroll
      for (int nn2 = 0; nn2 < 4; ++nn2) {
        kf[nn2] = *(const short8*)(Kp + (size_t)(nn2*16) * Dd + kc);
        vf[nn2] = *(const short8*)(Vp + (size_t)(nn2*16) * Dd + kc);
      }
      __builtin_amdgcn_s_setprio(1);
#pragma unroll
      for (int m = 0; m < 4; ++m)
#pragma unroll
        for (int nn2 = 0; nn2 < 4; ++nn2) {
          ak[m][nn2] = mfma16(af[m], kf[nn2], ak[m][nn2]);
          av[m][nn2] = mfma16(af[m], vf[nn2], av[m][nn2]);
        }
      __builtin_amdgcn_s_setprio(0);
    }
  }
  const int lr = lk * 4;
#pragma unroll
  for (int m = 0; m < 4; ++m)
#pragma unroll
    for (int nn2 = 0; nn2 < 4; ++nn2) {
      int row = bm + wr*64 + m*16 + lr;
      int col = bn + wc*64 + nn2*16 + li;
      f32x4 vk = ak[m][nn2];
#pragma unroll
      for (int r = 0; r < 4; ++r)
        Ck[(size_t)(row + r) * Dd + col] = f2b(vk[r]);
      f32x4 vv = av[m][nn2];
      union { u16 o[4]; short4v v4; } ou;
#pragma unroll
      for (int r = 0; r < 4; ++r) ou.o[r] = f2b(vv[r]);
      // vT[col][row..row+3] — 8B contiguous per lane
      *(short4v*)&CvT[(size_t)col * BN + row] = ou.v4;
    }
}

// ---------------- GEMM 64x64 (small M): ALL operands from global -------------
// Both A (activations, <=2 MB) and Bw (weights) are L2-resident. No LDS, no
// barriers: pure register pipeline (attn_b pattern). Grid is the occupancy
// limit anyway (64-256 blocks), latency hidden by K-loop unrolling.
// EP: 0 = bf16 out; 1 = f32 out + residual; 2 = bf16 out + bias + relu;
//     3 = f32 out + bias + residual
template<int EP>
__global__ __launch_bounds__(256) void gemm64(const u16* __restrict__ A,
    const u16* __restrict__ Bw, void* __restrict__ Cp,
    const float* __restrict__ bias, const float* __restrict__ res,
    int N, int K) {
  const int lane = threadIdx.x & 63, wid = threadIdx.x >> 6;
  const int wr = wid >> 1, wc = wid & 1;
  const int bm = blockIdx.y * 64, bn = blockIdx.x * 64;
  const int li = lane & 15, lk = lane >> 4;
  f32x4 acc[2][2] = {};
  const u16* Ap = A  + (size_t)(bm + wr*32 + li) * K + lk*8;
  const u16* Bp = Bw + (size_t)(bn + wc*32 + li) * K + lk*8;
#pragma unroll 4
  for (int k0 = 0; k0 < K; k0 += 32) {
    short8 af[2], bf[2];
    af[0] = *(const short8*)(Ap + k0);
    af[1] = *(const short8*)(Ap + (size_t)16*K + k0);
    bf[0] = *(const short8*)(Bp + k0);
    bf[1] = *(const short8*)(Bp + (size_t)16*K + k0);
#pragma unroll
    for (int m = 0; m < 2; ++m)
#pragma unroll
      for (int nn2 = 0; nn2 < 2; ++nn2)
        acc[m][nn2] = mfma16(af[m], bf[nn2], acc[m][nn2]);
  }
  const int lr = lk * 4;
#pragma unroll
  for (int m = 0; m < 2; ++m)
#pragma unroll
    for (int nn2 = 0; nn2 < 2; ++nn2) {
      int row = bm + wr*32 + m*16 + lr;
      int col = bn + wc*32 + nn2*16 + li;
      f32x4 v = acc[m][nn2];
#pragma unroll
      for (int r = 0; r < 4; ++r) {
        size_t off = (size_t)(row + r) * N + col;
        float x = v[r];
        if constexpr (EP == 0) ((u16*)Cp)[off] = f2b(x);
        else if constexpr (EP == 1) ((float*)Cp)[off] = x + res[off];
        else if constexpr (EP == 2) { x += bias[col]; ((u16*)Cp)[off] = f2b(x > 0.f ? x : 0.f); }
        else ((float*)Cp)[off] = x + bias[col] + res[off];
      }
    }
}

// ---------------- attention pass A: dots + column softmax + renorm prep ------
__global__ __launch_bounds__(256) void attn_a(const u16* __restrict__ q,
    const u16* __restrict__ kk, u16* __restrict__ attnb,
    float* __restrict__ rowsum, float* __restrict__ attn_mean) {
  const int jt = blockIdx.x, b = blockIdx.y;
  const int tid = threadIdx.x, lane = tid & 63, wid = tid >> 6;
  __shared__ float sc[64][129];   // [j_local][ih]
  __shared__ float red[4][64];
  const int li = lane & 15, lk = lane >> 4;
#pragma unroll
  for (int hh = 0; hh < 2; ++hh) {
    const int h = wid * 2 + hh;
    const u16* qb = q + (((size_t)b*16 + li)*8 + h)*64 + lk*8;
    short8 a0 = *(const short8*)qb;
    short8 a1 = *(const short8*)(qb + 32);
#pragma unroll
    for (int n = 0; n < 4; ++n) {
      const u16* kb = kk + ((size_t)b*Nn + jt*64 + n*16 + li)*Dd + h*64 + lk*8;
      f32x4 acc = {};
      acc = mfma16(a0, *(const short8*)kb, acc);
      acc = mfma16(a1, *(const short8*)(kb + 32), acc);
#pragma unroll
      for (int r = 0; r < 4; ++r)
        sc[n*16 + li][(lk*4 + r)*8 + h] = acc[r] * SCALE;
    }
  }
  __syncthreads();
  const int jl = tid & 63, qt = tid >> 6;
  float mx = -1e30f;
#pragma unroll
  for (int e = 0; e < 32; ++e) mx = fmaxf(mx, sc[jl][qt*32 + e]);
  red[qt][jl] = mx;
  __syncthreads();
  float M = fmaxf(fmaxf(red[0][jl], red[1][jl]), fmaxf(red[2][jl], red[3][jl]));
  __syncthreads();
  float s = 0.f;
#pragma unroll
  for (int e = 0; e < 32; ++e) {
    float ev = __expf(sc[jl][qt*32 + e] - M);
    sc[jl][qt*32 + e] = ev; s += ev;
  }
  red[qt][jl] = s;
  __syncthreads();
  float S = red[0][jl] + red[1][jl] + red[2][jl] + red[3][jl];
  float inv = 1.f / S;
#pragma unroll
  for (int e = 0; e < 32; ++e)
    sc[jl][qt*32 + e] = sc[jl][qt*32 + e] * inv + EPSR;   // attn_before + EPS
  __syncthreads();
  if (tid < 128) {
    float rs = 0.f;
    for (int j2 = 0; j2 < 64; ++j2) rs += sc[j2][tid];
    atomicAdd(&rowsum[b*128 + tid], rs);
  }
#pragma unroll
  for (int e = 0; e < 32; ++e) {
    int r = qt*32 + e;
    attnb[((size_t)b*128 + r)*Nn + jt*64 + jl] = f2b(sc[jl][r]);
  }
  if (attn_mean != nullptr && tid < 64) {
    for (int i = 0; i < 16; ++i) {
      float sm = 0.f;
#pragma unroll
      for (int h = 0; h < 8; ++h) sm += sc[tid][i*8 + h];
      attn_mean[((size_t)b*16 + i)*Nn + jt*64 + tid] = sm * 0.125f - EPSR;
    }
  }
}

// ---------------- attention pass B: partial updates = attn @ v ---------------
// vT layout: [d_out = h*64+d][b*N + j]. j split 4 ways for occupancy.
// Tpart layout: [js][b][h][i(16)][d(64)] f32.
__global__ __launch_bounds__(256) void attn_b(const u16* __restrict__ attnb,
    const u16* __restrict__ vT, float* __restrict__ Tpart) {
  const int h = blockIdx.x, js = blockIdx.y, b = blockIdx.z;
  const int lane = threadIdx.x & 63, wid = threadIdx.x >> 6;
  const int li = lane & 15, lk = lane >> 4;
  const size_t BN = (size_t)Bb * Nn;
  const int j0 = js * 1024;
  const u16* Ap = attnb + ((size_t)b*128 + li*8 + h)*Nn + j0 + lk*8;
  const u16* Bp = vT + (size_t)(h*64 + wid*16 + li)*BN + (size_t)b*Nn + j0 + lk*8;
  f32x4 acc[4] = {};
  for (int k0 = 0; k0 < 1024; k0 += 128) {
#pragma unroll
    for (int e = 0; e < 4; ++e)
      acc[e] = mfma16(*(const short8*)(Ap + k0 + e*32),
                      *(const short8*)(Bp + k0 + e*32), acc[e]);
  }
  float* Tout = Tpart + ((((size_t)js * Bb + b) * 8 + h) * 16) * 64;
#pragma unroll
  for (int r = 0; r < 4; ++r) {
    int i = lk*4 + r;
    float t = acc[0][r] + acc[1][r] + acc[2][r] + acc[3][r];
    Tout[(size_t)i * 64 + wid*16 + li] = t;
  }
}

// combine partials + renormalize: updb[(b*16+i)*512 + h*64+d]
__global__ void upd_c(const float* __restrict__ Tpart,
    const float* __restrict__ rs, u16* __restrict__ updb) {
  int idx = blockIdx.x * 256 + threadIdx.x;   // 262144 total
  int o = idx & 511, bi = idx >> 9;
  int b = bi >> 4, i = bi & 15;
  int h = o >> 6, d = o & 63;
  size_t base = (((size_t)b * 8 + h) * 16 + i) * 64 + d;
  const size_t stride = (size_t)Bb * 8 * 16 * 64;
  float t = Tpart[base] + Tpart[base + stride]
          + Tpart[base + 2*stride] + Tpart[base + 3*stride];
  updb[idx] = f2b(t / rs[b * 128 + i * 8 + h]);
}

// ---------------- small utility kernels --------------------------------------
__global__ void cvt_w(const float* __restrict__ s, u16* __restrict__ d, int n) {
  int i = blockIdx.x*256 + threadIdx.x;
  if (i < n) d[i] = f2b(s[i]);
}
// tiled transpose+convert: d[C][R] = bf16(s[R][C]^T)
__global__ __launch_bounds__(256) void tr_cvt(const float* __restrict__ s,
    u16* __restrict__ d, int R, int C) {
  __shared__ u16 t[32][33];
  const int c0 = blockIdx.x*32, r0 = blockIdx.y*32;
  const int tr = threadIdx.x >> 3, tc4 = (threadIdx.x & 7)*4;
  float4 v = *(const float4*)&s[(size_t)(r0+tr)*C + c0 + tc4];
  t[tr][tc4+0] = f2b(v.x); t[tr][tc4+1] = f2b(v.y);
  t[tr][tc4+2] = f2b(v.z); t[tr][tc4+3] = f2b(v.w);
  __syncthreads();
  const int oc = threadIdx.x >> 3, or4 = (threadIdx.x & 7)*4;
  union { u16 o[4]; short4v v4; } ou;
#pragma unroll
  for (int e = 0; e < 4; ++e) ou.o[e] = t[or4+e][oc];
  *(short4v*)&d[(size_t)(c0+oc)*R + r0 + or4] = ou.v4;
}
__global__ void copy_f32v4(const float* __restrict__ s, float* __restrict__ d, int n4) {
  int i = blockIdx.x*256 + threadIdx.x;
  if (i < n4) ((float4*)d)[i] = ((const float4*)s)[i];
}

extern "C" void kernel_launch(void* const* d_in, const int* in_sizes, int n_in,
                              void* d_out, int out_size, void* d_ws, size_t ws_size,
                              hipStream_t stream) {
  (void)in_sizes; (void)n_in; (void)out_size; (void)ws_size;
  const float* inputs  = (const float*)d_in[0];
  const float* cond    = (const float*)d_in[1];
  const float* ln_in_g = (const float*)d_in[2];
  const float* ln_in_b = (const float*)d_in[3];
  const float* Wk = (const float*)d_in[4];
  const float* Wv = (const float*)d_in[5];
  const float* Wq = (const float*)d_in[6];
  const float* Wo = (const float*)d_in[7];
  const float* ln_s_g = (const float*)d_in[8];
  const float* ln_s_b = (const float*)d_in[9];
  const float* ln_f_g = (const float*)d_in[10];
  const float* ln_f_b = (const float*)d_in[11];
  const float* W1 = (const float*)d_in[12];
  const float* b1 = (const float*)d_in[13];
  const float* W2 = (const float*)d_in[14];
  const float* b2 = (const float*)d_in[15];
  float* out_slots = (float*)d_out;
  float* out_amean = (float*)d_out + (size_t)Bb*NSs*Dd;

  char* w = (char*)d_ws;
  auto alloc = [&](size_t bytes) {
    char* p = w; w += (bytes + 255) & ~(size_t)255; return p;
  };
  u16*  xn    = (u16*)alloc((size_t)Bb*Nn*Dd*2);
  u16*  kbuf  = (u16*)alloc((size_t)Bb*Nn*Dd*2);
  u16*  vT    = (u16*)alloc((size_t)Bb*Nn*Dd*2);   // [512][B*N]
  u16*  attnb = (u16*)alloc((size_t)Bb*128*Nn*2);
  float* Tpart = (float*)alloc((size_t)4*Bb*8*16*64*4);  // [js][b][h][i][d]
  float* slots = (float*)alloc((size_t)Bb*NSs*Dd*4);
  u16*  qb    = (u16*)alloc((size_t)Bb*NSs*Dd*2);
  u16*  snb   = (u16*)alloc((size_t)Bb*NSs*Dd*2);
  u16*  s2nb  = (u16*)alloc((size_t)Bb*NSs*Dd*2);
  u16*  h1b   = (u16*)alloc((size_t)Bb*NSs*DFF*2);
  u16*  updb  = (u16*)alloc((size_t)Bb*NSs*Dd*2);
  float* rowsum = (float*)alloc((size_t)Bb*128*3*4);   // one per iteration
  u16*  wkb = (u16*)alloc(262144*2);
  u16*  wvb = (u16*)alloc(262144*2);
  u16*  wqb = (u16*)alloc(262144*2);
  u16*  wob = (u16*)alloc(262144*2);
  u16*  w1t = (u16*)alloc((size_t)1048576*2);
  u16*  w2t = (u16*)alloc((size_t)1048576*2);

  // weights -> bf16 (W1/W2 transposed so B-operand is [out,K] row-major)
  cvt_w<<<1024, 256, 0, stream>>>(Wk, wkb, 262144);
  cvt_w<<<1024, 256, 0, stream>>>(Wv, wvb, 262144);
  cvt_w<<<1024, 256, 0, stream>>>(Wq, wqb, 262144);
  cvt_w<<<1024, 256, 0, stream>>>(Wo, wob, 262144);
  tr_cvt<<<dim3(64, 16), 256, 0, stream>>>(W1, w1t, 512, 2048);
  tr_cvt<<<dim3(16, 64), 256, 0, stream>>>(W2, w2t, 2048, 512);
  // slots <- conditioning; rowsum <- 0 (all 3 iterations)
  copy_f32v4<<<256, 256, 0, stream>>>(cond, slots, 65536);
  (void)hipMemsetAsync(rowsum, 0, (size_t)Bb*128*3*4, stream);
  // x = LN(inputs) -> bf16
  ln_rows<<<Bb*Nn/4, 256, 0, stream>>>(inputs, ln_in_g, ln_in_b, xn, Bb*Nn);
  // fused: k = x @ Wk^T  [B*N,512]  and  vT = (x @ Wv^T)^T  [512, B*N]
  gemm_kv<<<4096, 256, 0, stream>>>(xn, wkb, wvb, kbuf, vT);

  for (int it = 0; it < 3; ++it) {
    float* rsp = rowsum + (size_t)it * Bb * 128;
    ln_rows<<<128, 256, 0, stream>>>(slots, ln_s_g, ln_s_b, snb, Bb*NSs);
    gemm64<0><<<dim3(8, 8), 256, 0, stream>>>(snb, wqb, qb, nullptr, nullptr, 512, 512);
    attn_a<<<dim3(Nn/64, Bb), 256, 0, stream>>>(qb, kbuf, attnb, rsp,
                                                it == 2 ? out_amean : nullptr);
    attn_b<<<dim3(Hh, 4, Bb), 256, 0, stream>>>(attnb, vT, Tpart);
    upd_c<<<1024, 256, 0, stream>>>(Tpart, rsp, updb);
    gemm64<1><<<dim3(8, 8), 256, 0, stream>>>(updb, wob, slots, nullptr, slots, 512, 512);
    ln_rows<<<128, 256, 0, stream>>>(slots, ln_f_g, ln_f_b, s2nb, Bb*NSs);
    gemm64<2><<<dim3(32, 8), 256, 0, stream>>>(s2nb, w1t, h1b, b1, nullptr, 2048, 512);
    gemm64<3><<<dim3(8, 8), 256, 0, stream>>>(h1b, w2t, slots, b2, slots, 512, 2048);
  }
  copy_f32v4<<<256, 256, 0, stream>>>(slots, out_slots, 65536);
}

// Round 10
// 730.217 us; speedup vs baseline: 1.1289x; 1.1289x over previous
//
#include <hip/hip_runtime.h>
#include <cstdint>
#include <cstddef>

typedef __attribute__((ext_vector_type(8))) short short8;
typedef __attribute__((ext_vector_type(4))) short short4v;
typedef __attribute__((ext_vector_type(8))) __bf16 bf16x8;
typedef __attribute__((ext_vector_type(4))) float f32x4;
typedef unsigned short u16;

static constexpr int Bb = 32, Nn = 4096, NSs = 16, Dd = 512, Hh = 8, DFF = 2048;
static constexpr float SCALE = 0.125f;   // (64)^-0.5
static constexpr float EPSR  = 1e-8f;
static constexpr float LN_EPS = 1e-5f;

__device__ __forceinline__ u16 f2b(float x) {
  union { float f; uint32_t u; } a; a.f = x;
  uint32_t r = a.u + 0x7fffu + ((a.u >> 16) & 1u);
  return (u16)(r >> 16);
}

__device__ __forceinline__ f32x4 mfma16(short8 a, short8 b, f32x4 c) {
  return __builtin_amdgcn_mfma_f32_16x16x32_bf16(
      __builtin_bit_cast(bf16x8, a), __builtin_bit_cast(bf16x8, b), c, 0, 0, 0);
}

// async global->LDS, 16B per lane; LDS dest must be wave-uniform base (+lane*16 HW)
__device__ __forceinline__ void gload16(const u16* g, u16* l) {
  __builtin_amdgcn_global_load_lds(
      (const __attribute__((address_space(1))) void*)g,
      (__attribute__((address_space(3))) void*)l, 16, 0, 0);
}

// ---------------- LayerNorm rows: fp32 [R,512] -> bf16 [R,512] ----------------
__global__ __launch_bounds__(256) void ln_rows(const float* __restrict__ src,
    const float* __restrict__ g, const float* __restrict__ bt,
    u16* __restrict__ dst, int R) {
  int row = blockIdx.x * 4 + (threadIdx.x >> 6);
  if (row >= R) return;
  int lane = threadIdx.x & 63;
  const float* p = src + (size_t)row * Dd + lane * 8;
  float4 u0 = *(const float4*)p;
  float4 u1 = *(const float4*)(p + 4);
  float x[8] = {u0.x,u0.y,u0.z,u0.w,u1.x,u1.y,u1.z,u1.w};
  float s = 0.f, s2 = 0.f;
#pragma unroll
  for (int e = 0; e < 8; ++e) { s += x[e]; s2 += x[e]*x[e]; }
#pragma unroll
  for (int m = 1; m < 64; m <<= 1) { s += __shfl_xor(s, m); s2 += __shfl_xor(s2, m); }
  float mean = s * (1.f/512.f);
  float var  = s2 * (1.f/512.f) - mean*mean;
  float rstd = rsqrtf(var + LN_EPS);
  union { u16 o[8]; short8 v; } ou;
#pragma unroll
  for (int e = 0; e < 8; ++e)
    ou.o[e] = f2b((x[e]-mean)*rstd*g[lane*8+e] + bt[lane*8+e]);
  *(short8*)(dst + (size_t)row * Dd + lane * 8) = ou.v;
}

// ---------------- fused K/V GEMM 128x128, BK=64 single-buffer (R6, 227us) ----
__global__ __launch_bounds__(256, 2) void gemm_kv(const u16* __restrict__ A,
    const u16* __restrict__ Bk, const u16* __restrict__ Bv,
    u16* __restrict__ Ck, u16* __restrict__ CvT) {
  __shared__ u16 lA[128*64];
  __shared__ u16 lK[128*64];
  __shared__ u16 lV[128*64];
  const int tid = threadIdx.x, lane = tid & 63, wid = tid >> 6;
  const int wr = wid >> 1, wc = wid & 1;
  const int n  = blockIdx.y * 4 + blockIdx.x;
  const int orig = (n & 7) * 512 + (n >> 3);
  const int bm = (orig >> 2) * 128, bn = (orig & 3) * 128;
  const size_t BN = (size_t)Bb * Nn;
  f32x4 ak[4][4] = {};
  f32x4 av[4][4] = {};
  const int sr = lane >> 3;
  const int ss = ((lane & 7) ^ (sr & 7)) * 8;   // swizzled source col (u16)
  const int li = lane & 15, lk = lane >> 4;
  const int sx = (li & 7) * 8;                  // read-side XOR (u16 units)
  for (int t = 0; t < 8; ++t) {
    const int k0 = t * 64;
    __syncthreads();
#pragma unroll
    for (int gi = 0; gi < 4; ++gi) {
      const int rb = wid * 32 + gi * 8;
      gload16(A  + (size_t)(bm + rb + sr) * Dd + k0 + ss, &lA[rb * 64]);
      gload16(Bk + (size_t)(bn + rb + sr) * Dd + k0 + ss, &lK[rb * 64]);
      gload16(Bv + (size_t)(bn + rb + sr) * Dd + k0 + ss, &lV[rb * 64]);
    }
    __syncthreads();
#pragma unroll
    for (int kk = 0; kk < 2; ++kk) {
      const int cs = ((kk * 4 + lk) * 8) ^ sx;
      short8 af[4], kf[4], vf[4];
#pragma unroll
      for (int m = 0; m < 4; ++m)
        af[m] = *(const short8*)&lA[(wr*64 + m*16 + li)*64 + cs];
#pragma unroll
      for (int nn2 = 0; nn2 < 4; ++nn2) {
        kf[nn2] = *(const short8*)&lK[(wc*64 + nn2*16 + li)*64 + cs];
        vf[nn2] = *(const short8*)&lV[(wc*64 + nn2*16 + li)*64 + cs];
      }
#pragma unroll
      for (int m = 0; m < 4; ++m)
#pragma unroll
        for (int nn2 = 0; nn2 < 4; ++nn2) {
          ak[m][nn2] = mfma16(af[m], kf[nn2], ak[m][nn2]);
          av[m][nn2] = mfma16(af[m], vf[nn2], av[m][nn2]);
        }
    }
  }
  const int lr = lk * 4;
#pragma unroll
  for (int m = 0; m < 4; ++m)
#pragma unroll
    for (int nn2 = 0; nn2 < 4; ++nn2) {
      int row = bm + wr*64 + m*16 + lr;
      int col = bn + wc*64 + nn2*16 + li;
      f32x4 vk = ak[m][nn2];
#pragma unroll
      for (int r = 0; r < 4; ++r)
        Ck[(size_t)(row + r) * Dd + col] = f2b(vk[r]);
      f32x4 vv = av[m][nn2];
      union { u16 o[4]; short4v v4; } ou;
#pragma unroll
      for (int r = 0; r < 4; ++r) ou.o[r] = f2b(vv[r]);
      *(short4v*)&CvT[(size_t)col * BN + row] = ou.v4;
    }
}

// ---------------- GEMM 64x64 (small M): operands straight from global --------
// EP: 0 = bf16 out; 1 = f32 out + residual; 2 = bf16 out + bias + relu;
//     3 = f32 out + bias + residual
template<int EP>
__global__ __launch_bounds__(256) void gemm64(const u16* __restrict__ A,
    const u16* __restrict__ Bw, void* __restrict__ Cp,
    const float* __restrict__ bias, const float* __restrict__ res,
    int N, int K) {
  const int lane = threadIdx.x & 63, wid = threadIdx.x >> 6;
  const int wr = wid >> 1, wc = wid & 1;
  const int bm = blockIdx.y * 64, bn = blockIdx.x * 64;
  const int li = lane & 15, lk = lane >> 4;
  f32x4 acc[2][2] = {};
  const u16* Ap = A  + (size_t)(bm + wr*32 + li) * K + lk*8;
  const u16* Bp = Bw + (size_t)(bn + wc*32 + li) * K + lk*8;
#pragma unroll 4
  for (int k0 = 0; k0 < K; k0 += 32) {
    short8 af[2], bf[2];
    af[0] = *(const short8*)(Ap + k0);
    af[1] = *(const short8*)(Ap + (size_t)16*K + k0);
    bf[0] = *(const short8*)(Bp + k0);
    bf[1] = *(const short8*)(Bp + (size_t)16*K + k0);
#pragma unroll
    for (int m = 0; m < 2; ++m)
#pragma unroll
      for (int nn2 = 0; nn2 < 2; ++nn2)
        acc[m][nn2] = mfma16(af[m], bf[nn2], acc[m][nn2]);
  }
  const int lr = lk * 4;
#pragma unroll
  for (int m = 0; m < 2; ++m)
#pragma unroll
    for (int nn2 = 0; nn2 < 2; ++nn2) {
      int row = bm + wr*32 + m*16 + lr;
      int col = bn + wc*32 + nn2*16 + li;
      f32x4 v = acc[m][nn2];
#pragma unroll
      for (int r = 0; r < 4; ++r) {
        size_t off = (size_t)(row + r) * N + col;
        float x = v[r];
        if constexpr (EP == 0) ((u16*)Cp)[off] = f2b(x);
        else if constexpr (EP == 1) ((float*)Cp)[off] = x + res[off];
        else if constexpr (EP == 2) { x += bias[col]; ((u16*)Cp)[off] = f2b(x > 0.f ? x : 0.f); }
        else ((float*)Cp)[off] = x + bias[col] + res[off];
      }
    }
}

// ---------------- FUSED attention: dots + col-softmax + P@V, no attnb -------
// Softmax is over (slots*heads), i.e. LOCAL per column j -> the full attention
// can be computed per j-tile without materializing attnb. grid (8 js, B);
// 512 threads = 8 waves, one head per wave. Per j-tile of 64:
//   dots (MFMA, K frags from global) -> sc[64 j][128 ih] -> column softmax ->
//   P2[h][i][j] bf16 in LDS (head-major, 72-u16 rows = 144B: 16B-aligned,
//   2-way-conflict-free) -> PV MFMA (V frags from vT global) accumulated in
//   registers across 8 tiles. Partial sums -> Tpart[js]; rowsum via one
//   atomicAdd per thread at the end.
__global__ __launch_bounds__(512) void attn_f(const u16* __restrict__ q,
    const u16* __restrict__ kk, const u16* __restrict__ vT,
    float* __restrict__ rowsum, float* __restrict__ Tpart,
    float* __restrict__ attn_mean) {
  const int js = blockIdx.x, b = blockIdx.y;
  const int tid = threadIdx.x, lane = tid & 63;
  const int h = tid >> 6;                  // wave id = head
  __shared__ float sc[64][129];
  __shared__ float red[8][64];
  __shared__ u16 P2[8][16][72];
  const int li = lane & 15, lk = lane >> 4;
  const size_t BN = (size_t)Bb * Nn;
  // q fragments for this head (hoisted across all 8 j-tiles)
  const u16* qb = q + (((size_t)b*16 + li)*8 + h)*64 + lk*8;
  short8 a0 = *(const short8*)qb;
  short8 a1 = *(const short8*)(qb + 32);
  f32x4 apv[4] = {};
  float rs_acc = 0.f;
  const int jl = tid & 63, qt = tid >> 6;
  for (int t2 = 0; t2 < 8; ++t2) {
    const int j0 = js * 512 + t2 * 64;
    // ---- dots: sc[j][ih] = q.k * SCALE ----
#pragma unroll
    for (int n = 0; n < 4; ++n) {
      const u16* kb = kk + ((size_t)b*Nn + j0 + n*16 + li)*Dd + h*64 + lk*8;
      f32x4 acc = {};
      acc = mfma16(a0, *(const short8*)kb, acc);
      acc = mfma16(a1, *(const short8*)(kb + 32), acc);
#pragma unroll
      for (int r = 0; r < 4; ++r)
        sc[n*16 + li][(lk*4 + r)*8 + h] = acc[r] * SCALE;
    }
    __syncthreads();
    // ---- column softmax over 128 ih (thread = (jl, qt), 16 elems each) ----
    float mx = -1e30f;
#pragma unroll
    for (int e = 0; e < 16; ++e) mx = fmaxf(mx, sc[jl][qt*16 + e]);
    red[qt][jl] = mx;
    __syncthreads();
    float M = red[0][jl];
#pragma unroll
    for (int p = 1; p < 8; ++p) M = fmaxf(M, red[p][jl]);
    __syncthreads();
    float s = 0.f;
#pragma unroll
    for (int e = 0; e < 16; ++e) {
      float ev = __expf(sc[jl][qt*16 + e] - M);
      sc[jl][qt*16 + e] = ev; s += ev;
    }
    red[qt][jl] = s;
    __syncthreads();
    float S = red[0][jl];
#pragma unroll
    for (int p = 1; p < 8; ++p) S += red[p][jl];
    float inv = 1.f / S;
#pragma unroll
    for (int e = 0; e < 16; ++e) {
      int ih = qt*16 + e;
      float a = sc[jl][ih] * inv + EPSR;     // attn_before + EPS
      sc[jl][ih] = a;
      P2[ih & 7][ih >> 3][jl] = f2b(a);
    }
    __syncthreads();
    // ---- rowsum accumulation (ih = tid for tid<128) ----
    if (tid < 128) {
      float rs = 0.f;
      for (int j2 = 0; j2 < 64; ++j2) rs += sc[j2][tid];
      rs_acc += rs;
    }
    // ---- attn_mean (final iteration only) ----
    if (attn_mean != nullptr && tid < 64) {
      for (int i = 0; i < 16; ++i) {
        float sm = 0.f;
#pragma unroll
        for (int hh = 0; hh < 8; ++hh) sm += sc[tid][i*8 + hh];
        attn_mean[((size_t)b*16 + i)*Nn + j0 + tid] = sm * 0.125f - EPSR;
      }
    }
    // ---- PV: apv[n] += P_h[i][j] * V_h[j][d] ----
#pragma unroll
    for (int n = 0; n < 4; ++n) {
      const u16* vb = vT + (size_t)(h*64 + n*16 + li)*BN + (size_t)b*Nn + j0 + lk*8;
      short8 b0 = *(const short8*)vb;
      short8 b1 = *(const short8*)(vb + 32);
      short8 pa0 = *(const short8*)&P2[h][li][lk*8];
      short8 pa1 = *(const short8*)&P2[h][li][32 + lk*8];
      apv[n] = mfma16(pa0, b0, apv[n]);
      apv[n] = mfma16(pa1, b1, apv[n]);
    }
    __syncthreads();   // sc/P2 free for next tile
  }
  float* Tout = Tpart + (((size_t)js * Bb + b) * 8 + h) * 16 * 64;
#pragma unroll
  for (int n = 0; n < 4; ++n)
#pragma unroll
    for (int r = 0; r < 4; ++r)
      Tout[(size_t)(lk*4 + r) * 64 + n*16 + li] = apv[n][r];
  if (tid < 128) atomicAdd(&rowsum[b*128 + tid], rs_acc);
}

// combine partials + renormalize: updb[(b*16+i)*512 + h*64+d]
__global__ void upd_c(const float* __restrict__ Tpart,
    const float* __restrict__ rs, u16* __restrict__ updb) {
  int idx = blockIdx.x * 256 + threadIdx.x;   // 262144 total
  int o = idx & 511, bi = idx >> 9;
  int b = bi >> 4, i = bi & 15;
  int h = o >> 6, d = o & 63;
  size_t base = (((size_t)b * 8 + h) * 16 + i) * 64 + d;
  const size_t stride = (size_t)Bb * 8 * 16 * 64;
  float t = 0.f;
#pragma unroll
  for (int p = 0; p < 8; ++p) t += Tpart[base + p * stride];
  updb[idx] = f2b(t / rs[b * 128 + i * 8 + h]);
}

// ---------------- small utility kernels --------------------------------------
__global__ void cvt_w(const float* __restrict__ s, u16* __restrict__ d, int n) {
  int i = blockIdx.x*256 + threadIdx.x;
  if (i < n) d[i] = f2b(s[i]);
}
// tiled transpose+convert: d[C][R] = bf16(s[R][C]^T)
__global__ __launch_bounds__(256) void tr_cvt(const float* __restrict__ s,
    u16* __restrict__ d, int R, int C) {
  __shared__ u16 t[32][33];
  const int c0 = blockIdx.x*32, r0 = blockIdx.y*32;
  const int tr = threadIdx.x >> 3, tc4 = (threadIdx.x & 7)*4;
  float4 v = *(const float4*)&s[(size_t)(r0+tr)*C + c0 + tc4];
  t[tr][tc4+0] = f2b(v.x); t[tr][tc4+1] = f2b(v.y);
  t[tr][tc4+2] = f2b(v.z); t[tr][tc4+3] = f2b(v.w);
  __syncthreads();
  const int oc = threadIdx.x >> 3, or4 = (threadIdx.x & 7)*4;
  union { u16 o[4]; short4v v4; } ou;
#pragma unroll
  for (int e = 0; e < 4; ++e) ou.o[e] = t[or4+e][oc];
  *(short4v*)&d[(size_t)(c0+oc)*R + r0 + or4] = ou.v4;
}
__global__ void copy_f32v4(const float* __restrict__ s, float* __restrict__ d, int n4) {
  int i = blockIdx.x*256 + threadIdx.x;
  if (i < n4) ((float4*)d)[i] = ((const float4*)s)[i];
}

extern "C" void kernel_launch(void* const* d_in, const int* in_sizes, int n_in,
                              void* d_out, int out_size, void* d_ws, size_t ws_size,
                              hipStream_t stream) {
  (void)in_sizes; (void)n_in; (void)out_size; (void)ws_size;
  const float* inputs  = (const float*)d_in[0];
  const float* cond    = (const float*)d_in[1];
  const float* ln_in_g = (const float*)d_in[2];
  const float* ln_in_b = (const float*)d_in[3];
  const float* Wk = (const float*)d_in[4];
  const float* Wv = (const float*)d_in[5];
  const float* Wq = (const float*)d_in[6];
  const float* Wo = (const float*)d_in[7];
  const float* ln_s_g = (const float*)d_in[8];
  const float* ln_s_b = (const float*)d_in[9];
  const float* ln_f_g = (const float*)d_in[10];
  const float* ln_f_b = (const float*)d_in[11];
  const float* W1 = (const float*)d_in[12];
  const float* b1 = (const float*)d_in[13];
  const float* W2 = (const float*)d_in[14];
  const float* b2 = (const float*)d_in[15];
  float* out_slots = (float*)d_out;
  float* out_amean = (float*)d_out + (size_t)Bb*NSs*Dd;

  char* w = (char*)d_ws;
  auto alloc = [&](size_t bytes) {
    char* p = w; w += (bytes + 255) & ~(size_t)255; return p;
  };
  u16*  xn    = (u16*)alloc((size_t)Bb*Nn*Dd*2);
  u16*  kbuf  = (u16*)alloc((size_t)Bb*Nn*Dd*2);
  u16*  vT    = (u16*)alloc((size_t)Bb*Nn*Dd*2);   // [512][B*N]
  float* Tpart = (float*)alloc((size_t)8*Bb*8*16*64*4);  // [js][b][h][i][d]
  float* slots = (float*)alloc((size_t)Bb*NSs*Dd*4);
  u16*  qb    = (u16*)alloc((size_t)Bb*NSs*Dd*2);
  u16*  snb   = (u16*)alloc((size_t)Bb*NSs*Dd*2);
  u16*  s2nb  = (u16*)alloc((size_t)Bb*NSs*Dd*2);
  u16*  h1b   = (u16*)alloc((size_t)Bb*NSs*DFF*2);
  u16*  updb  = (u16*)alloc((size_t)Bb*NSs*Dd*2);
  float* rowsum = (float*)alloc((size_t)Bb*128*3*4);   // one per iteration
  u16*  wkb = (u16*)alloc(262144*2);
  u16*  wvb = (u16*)alloc(262144*2);
  u16*  wqb = (u16*)alloc(262144*2);
  u16*  wob = (u16*)alloc(262144*2);
  u16*  w1t = (u16*)alloc((size_t)1048576*2);
  u16*  w2t = (u16*)alloc((size_t)1048576*2);

  // weights -> bf16 (W1/W2 transposed so B-operand is [out,K] row-major)
  cvt_w<<<1024, 256, 0, stream>>>(Wk, wkb, 262144);
  cvt_w<<<1024, 256, 0, stream>>>(Wv, wvb, 262144);
  cvt_w<<<1024, 256, 0, stream>>>(Wq, wqb, 262144);
  cvt_w<<<1024, 256, 0, stream>>>(Wo, wob, 262144);
  tr_cvt<<<dim3(64, 16), 256, 0, stream>>>(W1, w1t, 512, 2048);
  tr_cvt<<<dim3(16, 64), 256, 0, stream>>>(W2, w2t, 2048, 512);
  // slots <- conditioning; rowsum <- 0 (all 3 iterations)
  copy_f32v4<<<256, 256, 0, stream>>>(cond, slots, 65536);
  (void)hipMemsetAsync(rowsum, 0, (size_t)Bb*128*3*4, stream);
  // x = LN(inputs) -> bf16
  ln_rows<<<Bb*Nn/4, 256, 0, stream>>>(inputs, ln_in_g, ln_in_b, xn, Bb*Nn);
  // fused: k = x @ Wk^T  [B*N,512]  and  vT = (x @ Wv^T)^T  [512, B*N]
  gemm_kv<<<dim3(4, Bb*Nn/128), 256, 0, stream>>>(xn, wkb, wvb, kbuf, vT);

  for (int it = 0; it < 3; ++it) {
    float* rsp = rowsum + (size_t)it * Bb * 128;
    ln_rows<<<128, 256, 0, stream>>>(slots, ln_s_g, ln_s_b, snb, Bb*NSs);
    gemm64<0><<<dim3(8, 8), 256, 0, stream>>>(snb, wqb, qb, nullptr, nullptr, 512, 512);
    attn_f<<<dim3(8, Bb), 512, 0, stream>>>(qb, kbuf, vT, rsp, Tpart,
                                            it == 2 ? out_amean : nullptr);
    upd_c<<<1024, 256, 0, stream>>>(Tpart, rsp, updb);
    gemm64<1><<<dim3(8, 8), 256, 0, stream>>>(updb, wob, slots, nullptr, slots, 512, 512);
    ln_rows<<<128, 256, 0, stream>>>(slots, ln_f_g, ln_f_b, s2nb, Bb*NSs);
    gemm64<2><<<dim3(32, 8), 256, 0, stream>>>(s2nb, w1t, h1b, b1, nullptr, 2048, 512);
    gemm64<3><<<dim3(8, 8), 256, 0, stream>>>(h1b, w2t, slots, b2, slots, 512, 2048);
  }
  copy_f32v4<<<256, 256, 0, stream>>>(slots, out_slots, 65536);
}

// Round 11
// 702.008 us; speedup vs baseline: 1.1743x; 1.0402x over previous
//
#include <hip/hip_runtime.h>
#include <cstdint>
#include <cstddef>

typedef __attribute__((ext_vector_type(8))) short short8;
typedef __attribute__((ext_vector_type(4))) short short4v;
typedef __attribute__((ext_vector_type(8))) __bf16 bf16x8;
typedef __attribute__((ext_vector_type(4))) float f32x4;
typedef unsigned short u16;

static constexpr int Bb = 32, Nn = 4096, NSs = 16, Dd = 512, Hh = 8, DFF = 2048;
static constexpr float SCALE = 0.125f;   // (64)^-0.5
static constexpr float EPSR  = 1e-8f;
static constexpr float LN_EPS = 1e-5f;
static constexpr int JS = 16;            // j-splits in attn_f

__device__ __forceinline__ u16 f2b(float x) {
  union { float f; uint32_t u; } a; a.f = x;
  uint32_t r = a.u + 0x7fffu + ((a.u >> 16) & 1u);
  return (u16)(r >> 16);
}
__device__ __forceinline__ float b2f(u16 x) {
  union { uint32_t u; float f; } a; a.u = ((uint32_t)x) << 16; return a.f;
}

__device__ __forceinline__ f32x4 mfma16(short8 a, short8 b, f32x4 c) {
  return __builtin_amdgcn_mfma_f32_16x16x32_bf16(
      __builtin_bit_cast(bf16x8, a), __builtin_bit_cast(bf16x8, b), c, 0, 0, 0);
}

// async global->LDS, 16B per lane; LDS dest must be wave-uniform base (+lane*16 HW)
__device__ __forceinline__ void gload16(const u16* g, u16* l) {
  __builtin_amdgcn_global_load_lds(
      (const __attribute__((address_space(1))) void*)g,
      (__attribute__((address_space(3))) void*)l, 16, 0, 0);
}

// ---------------- LayerNorm rows: fp32 [R,512] -> bf16 [R,512] ----------------
__global__ __launch_bounds__(256) void ln_rows(const float* __restrict__ src,
    const float* __restrict__ g, const float* __restrict__ bt,
    u16* __restrict__ dst, int R) {
  int row = blockIdx.x * 4 + (threadIdx.x >> 6);
  if (row >= R) return;
  int lane = threadIdx.x & 63;
  const float* p = src + (size_t)row * Dd + lane * 8;
  float4 u0 = *(const float4*)p;
  float4 u1 = *(const float4*)(p + 4);
  float x[8] = {u0.x,u0.y,u0.z,u0.w,u1.x,u1.y,u1.z,u1.w};
  float s = 0.f, s2 = 0.f;
#pragma unroll
  for (int e = 0; e < 8; ++e) { s += x[e]; s2 += x[e]*x[e]; }
#pragma unroll
  for (int m = 1; m < 64; m <<= 1) { s += __shfl_xor(s, m); s2 += __shfl_xor(s2, m); }
  float mean = s * (1.f/512.f);
  float var  = s2 * (1.f/512.f) - mean*mean;
  float rstd = rsqrtf(var + LN_EPS);
  union { u16 o[8]; short8 v; } ou;
#pragma unroll
  for (int e = 0; e < 8; ++e)
    ou.o[e] = f2b((x[e]-mean)*rstd*g[lane*8+e] + bt[lane*8+e]);
  *(short8*)(dst + (size_t)row * Dd + lane * 8) = ou.v;
}

// ---------------- fused K/V GEMM 128x128, BK=64 single-buffer (R6, 227us) ----
__global__ __launch_bounds__(256, 2) void gemm_kv(const u16* __restrict__ A,
    const u16* __restrict__ Bk, const u16* __restrict__ Bv,
    u16* __restrict__ Ck, u16* __restrict__ CvT) {
  __shared__ u16 lA[128*64];
  __shared__ u16 lK[128*64];
  __shared__ u16 lV[128*64];
  const int tid = threadIdx.x, lane = tid & 63, wid = tid >> 6;
  const int wr = wid >> 1, wc = wid & 1;
  const int n  = blockIdx.y * 4 + blockIdx.x;
  const int orig = (n & 7) * 512 + (n >> 3);
  const int bm = (orig >> 2) * 128, bn = (orig & 3) * 128;
  const size_t BN = (size_t)Bb * Nn;
  f32x4 ak[4][4] = {};
  f32x4 av[4][4] = {};
  const int sr = lane >> 3;
  const int ss = ((lane & 7) ^ (sr & 7)) * 8;   // swizzled source col (u16)
  const int li = lane & 15, lk = lane >> 4;
  const int sx = (li & 7) * 8;                  // read-side XOR (u16 units)
  for (int t = 0; t < 8; ++t) {
    const int k0 = t * 64;
    __syncthreads();
#pragma unroll
    for (int gi = 0; gi < 4; ++gi) {
      const int rb = wid * 32 + gi * 8;
      gload16(A  + (size_t)(bm + rb + sr) * Dd + k0 + ss, &lA[rb * 64]);
      gload16(Bk + (size_t)(bn + rb + sr) * Dd + k0 + ss, &lK[rb * 64]);
      gload16(Bv + (size_t)(bn + rb + sr) * Dd + k0 + ss, &lV[rb * 64]);
    }
    __syncthreads();
#pragma unroll
    for (int kk = 0; kk < 2; ++kk) {
      const int cs = ((kk * 4 + lk) * 8) ^ sx;
      short8 af[4], kf[4], vf[4];
#pragma unroll
      for (int m = 0; m < 4; ++m)
        af[m] = *(const short8*)&lA[(wr*64 + m*16 + li)*64 + cs];
#pragma unroll
      for (int nn2 = 0; nn2 < 4; ++nn2) {
        kf[nn2] = *(const short8*)&lK[(wc*64 + nn2*16 + li)*64 + cs];
        vf[nn2] = *(const short8*)&lV[(wc*64 + nn2*16 + li)*64 + cs];
      }
#pragma unroll
      for (int m = 0; m < 4; ++m)
#pragma unroll
        for (int nn2 = 0; nn2 < 4; ++nn2) {
          ak[m][nn2] = mfma16(af[m], kf[nn2], ak[m][nn2]);
          av[m][nn2] = mfma16(af[m], vf[nn2], av[m][nn2]);
        }
    }
  }
  const int lr = lk * 4;
#pragma unroll
  for (int m = 0; m < 4; ++m)
#pragma unroll
    for (int nn2 = 0; nn2 < 4; ++nn2) {
      int row = bm + wr*64 + m*16 + lr;
      int col = bn + wc*64 + nn2*16 + li;
      f32x4 vk = ak[m][nn2];
#pragma unroll
      for (int r = 0; r < 4; ++r)
        Ck[(size_t)(row + r) * Dd + col] = f2b(vk[r]);
      f32x4 vv = av[m][nn2];
      union { u16 o[4]; short4v v4; } ou;
#pragma unroll
      for (int r = 0; r < 4; ++r) ou.o[r] = f2b(vv[r]);
      *(short4v*)&CvT[(size_t)col * BN + row] = ou.v4;
    }
}

// ---------------- GEMM 64x64 (small M): operands straight from global --------
// EP: 0 = bf16 out; 1 = f32 out + residual; 2 = bf16 out + bias + relu;
//     3 = f32 out + bias + residual
template<int EP>
__global__ __launch_bounds__(256) void gemm64(const u16* __restrict__ A,
    const u16* __restrict__ Bw, void* __restrict__ Cp,
    const float* __restrict__ bias, const float* __restrict__ res,
    int N, int K) {
  const int lane = threadIdx.x & 63, wid = threadIdx.x >> 6;
  const int wr = wid >> 1, wc = wid & 1;
  const int bm = blockIdx.y * 64, bn = blockIdx.x * 64;
  const int li = lane & 15, lk = lane >> 4;
  f32x4 acc[2][2] = {};
  const u16* Ap = A  + (size_t)(bm + wr*32 + li) * K + lk*8;
  const u16* Bp = Bw + (size_t)(bn + wc*32 + li) * K + lk*8;
#pragma unroll 4
  for (int k0 = 0; k0 < K; k0 += 32) {
    short8 af[2], bf[2];
    af[0] = *(const short8*)(Ap + k0);
    af[1] = *(const short8*)(Ap + (size_t)16*K + k0);
    bf[0] = *(const short8*)(Bp + k0);
    bf[1] = *(const short8*)(Bp + (size_t)16*K + k0);
#pragma unroll
    for (int m = 0; m < 2; ++m)
#pragma unroll
      for (int nn2 = 0; nn2 < 2; ++nn2)
        acc[m][nn2] = mfma16(af[m], bf[nn2], acc[m][nn2]);
  }
  const int lr = lk * 4;
#pragma unroll
  for (int m = 0; m < 2; ++m)
#pragma unroll
    for (int nn2 = 0; nn2 < 2; ++nn2) {
      int row = bm + wr*32 + m*16 + lr;
      int col = bn + wc*32 + nn2*16 + li;
      f32x4 v = acc[m][nn2];
#pragma unroll
      for (int r = 0; r < 4; ++r) {
        size_t off = (size_t)(row + r) * N + col;
        float x = v[r];
        if constexpr (EP == 0) ((u16*)Cp)[off] = f2b(x);
        else if constexpr (EP == 1) ((float*)Cp)[off] = x + res[off];
        else if constexpr (EP == 2) { x += bias[col]; ((u16*)Cp)[off] = f2b(x > 0.f ? x : 0.f); }
        else ((float*)Cp)[off] = x + bias[col] + res[off];
      }
    }
}

// ---------------- FUSED attention v2: register softmax, 2 blocks/CU ----------
// grid (JS=16 j-splits, B); 512 thr = 8 waves, wave = head. Per 64-j tile:
// dots in registers -> column max/sum via shfl(lk) + redM/redS[8][64] cross-
// wave -> P bf16 into P2[8][16][72] (wave-local consumption) -> PV MFMA.
// No 33KB sc array (R10): LDS 22KB, VGPR<=128 -> 2 blocks/CU resident.
__global__ __launch_bounds__(512, 4) void attn_f(const u16* __restrict__ q,
    const u16* __restrict__ kk, const u16* __restrict__ vT,
    float* __restrict__ rowsum, float* __restrict__ Tpart,
    float* __restrict__ attn_mean) {
  const int js = blockIdx.x, b = blockIdx.y;
  const int tid = threadIdx.x, lane = tid & 63, h = tid >> 6;
  __shared__ float redM[8][64];
  __shared__ float redS[8][64];
  __shared__ u16 P2[8][16][72];
  const int li = lane & 15, lk = lane >> 4;
  const size_t BN = (size_t)Bb * Nn;
  const u16* qb = q + (((size_t)b*16 + li)*8 + h)*64 + lk*8;
  short8 a0 = *(const short8*)qb;
  short8 a1 = *(const short8*)(qb + 32);
  f32x4 apv[4] = {};
  float rs_acc[4] = {0.f, 0.f, 0.f, 0.f};
  for (int t2 = 0; t2 < 4; ++t2) {
    const int j0 = js * 256 + t2 * 64;
    // ---- dots in registers: dt[n][r] = dots[j=n*16+li][ih=(lk*4+r)*8+h] ----
    f32x4 dt[4];
#pragma unroll
    for (int n = 0; n < 4; ++n) {
      const u16* kb = kk + ((size_t)b*Nn + j0 + n*16 + li)*Dd + h*64 + lk*8;
      f32x4 acc = {};
      acc = mfma16(a0, *(const short8*)kb, acc);
      acc = mfma16(a1, *(const short8*)(kb + 32), acc);
#pragma unroll
      for (int r = 0; r < 4; ++r) dt[n][r] = acc[r] * SCALE;
    }
    // ---- wave-local column max (reduce r in-lane, lk via shfl) ----
#pragma unroll
    for (int n = 0; n < 4; ++n) {
      float v = fmaxf(fmaxf(dt[n][0], dt[n][1]), fmaxf(dt[n][2], dt[n][3]));
      v = fmaxf(v, __shfl_xor(v, 16));
      v = fmaxf(v, __shfl_xor(v, 32));
      if (lk == 0) redM[h][n*16 + li] = v;
    }
    __syncthreads();                       // redM complete (s1)
    float M[4];
#pragma unroll
    for (int n = 0; n < 4; ++n) {
      float m2 = redM[0][n*16 + li];
#pragma unroll
      for (int p = 1; p < 8; ++p) m2 = fmaxf(m2, redM[p][n*16 + li]);
      M[n] = m2;
    }
    // ---- exp + wave-local column sum ----
#pragma unroll
    for (int n = 0; n < 4; ++n) {
      float s = 0.f;
#pragma unroll
      for (int r = 0; r < 4; ++r) { dt[n][r] = __expf(dt[n][r] - M[n]); s += dt[n][r]; }
      s += __shfl_xor(s, 16);
      s += __shfl_xor(s, 32);
      if (lk == 0) redS[h][n*16 + li] = s;
    }
    __syncthreads();                       // redS complete (s2); redM reads done
#pragma unroll
    for (int n = 0; n < 4; ++n) {
      float s2 = redS[0][n*16 + li];
#pragma unroll
      for (int p = 1; p < 8; ++p) s2 += redS[p][n*16 + li];
      float inv = 1.f / s2;
#pragma unroll
      for (int r = 0; r < 4; ++r) dt[n][r] = dt[n][r] * inv + EPSR;  // attn+EPS
    }
    // ---- P -> LDS bf16 (consumed by SAME wave in PV; no barrier needed) ----
#pragma unroll
    for (int n = 0; n < 4; ++n)
#pragma unroll
      for (int r = 0; r < 4; ++r)
        P2[h][lk*4 + r][n*16 + li] = f2b(dt[n][r]);
    // ---- rowsum partials: sum over j (n in-lane, li via shfl) ----
#pragma unroll
    for (int r = 0; r < 4; ++r) {
      float v = dt[0][r] + dt[1][r] + dt[2][r] + dt[3][r];
      v += __shfl_xor(v, 1); v += __shfl_xor(v, 2);
      v += __shfl_xor(v, 4); v += __shfl_xor(v, 8);
      rs_acc[r] += v;                      // li==0 lanes hold column-group sum
    }
    // ---- PV: apv[n] += P_h[i][j] * V_h[j][d] ----
    short8 pa0 = *(const short8*)&P2[h][li][lk*8];
    short8 pa1 = *(const short8*)&P2[h][li][32 + lk*8];
#pragma unroll
    for (int n = 0; n < 4; ++n) {
      const u16* vb = vT + (size_t)(h*64 + n*16 + li)*BN + (size_t)b*Nn + j0 + lk*8;
      apv[n] = mfma16(pa0, *(const short8*)vb, apv[n]);
      apv[n] = mfma16(pa1, *(const short8*)(vb + 32), apv[n]);
    }
    // ---- attn_mean (last iteration only): cross-wave read of P2 ----
    if (attn_mean != nullptr) {
      __syncthreads();                     // all P2 writes visible
      int j = tid & 63;
#pragma unroll
      for (int ii = 0; ii < 2; ++ii) {
        int i = (tid >> 6) + ii*8;
        float sm = 0.f;
#pragma unroll
        for (int hh = 0; hh < 8; ++hh) sm += b2f(P2[hh][i][j]);
        attn_mean[((size_t)b*16 + i)*Nn + j0 + j] = sm * 0.125f - EPSR;
      }
      __syncthreads();                     // reads done before next-tile writes
    }
  }
  float* Tout = Tpart + (((size_t)js * Bb + b) * 8 + h) * 16 * 64;
#pragma unroll
  for (int n = 0; n < 4; ++n)
#pragma unroll
    for (int r = 0; r < 4; ++r)
      Tout[(size_t)(lk*4 + r) * 64 + n*16 + li] = apv[n][r];
  if (li == 0)
#pragma unroll
    for (int r = 0; r < 4; ++r)
      atomicAdd(&rowsum[b*128 + (lk*4 + r)*8 + h], rs_acc[r]);
}

// combine partials + renormalize: updb[(b*16+i)*512 + h*64+d]
__global__ void upd_c(const float* __restrict__ Tpart,
    const float* __restrict__ rs, u16* __restrict__ updb) {
  int idx = blockIdx.x * 256 + threadIdx.x;   // 262144 total
  int o = idx & 511, bi = idx >> 9;
  int b = bi >> 4, i = bi & 15;
  int h = o >> 6, d = o & 63;
  size_t base = (((size_t)b * 8 + h) * 16 + i) * 64 + d;
  const size_t stride = (size_t)Bb * 8 * 16 * 64;
  float t = 0.f;
#pragma unroll
  for (int p = 0; p < JS; ++p) t += Tpart[base + p * stride];
  updb[idx] = f2b(t / rs[b * 128 + i * 8 + h]);
}

// ---------------- small utility kernels --------------------------------------
__global__ void cvt_w(const float* __restrict__ s, u16* __restrict__ d, int n) {
  int i = blockIdx.x*256 + threadIdx.x;
  if (i < n) d[i] = f2b(s[i]);
}
// tiled transpose+convert: d[C][R] = bf16(s[R][C]^T)
__global__ __launch_bounds__(256) void tr_cvt(const float* __restrict__ s,
    u16* __restrict__ d, int R, int C) {
  __shared__ u16 t[32][33];
  const int c0 = blockIdx.x*32, r0 = blockIdx.y*32;
  const int tr = threadIdx.x >> 3, tc4 = (threadIdx.x & 7)*4;
  float4 v = *(const float4*)&s[(size_t)(r0+tr)*C + c0 + tc4];
  t[tr][tc4+0] = f2b(v.x); t[tr][tc4+1] = f2b(v.y);
  t[tr][tc4+2] = f2b(v.z); t[tr][tc4+3] = f2b(v.w);
  __syncthreads();
  const int oc = threadIdx.x >> 3, or4 = (threadIdx.x & 7)*4;
  union { u16 o[4]; short4v v4; } ou;
#pragma unroll
  for (int e = 0; e < 4; ++e) ou.o[e] = t[or4+e][oc];
  *(short4v*)&d[(size_t)(c0+oc)*R + r0 + or4] = ou.v4;
}
__global__ void copy_f32v4(const float* __restrict__ s, float* __restrict__ d, int n4) {
  int i = blockIdx.x*256 + threadIdx.x;
  if (i < n4) ((float4*)d)[i] = ((const float4*)s)[i];
}

extern "C" void kernel_launch(void* const* d_in, const int* in_sizes, int n_in,
                              void* d_out, int out_size, void* d_ws, size_t ws_size,
                              hipStream_t stream) {
  (void)in_sizes; (void)n_in; (void)out_size; (void)ws_size;
  const float* inputs  = (const float*)d_in[0];
  const float* cond    = (const float*)d_in[1];
  const float* ln_in_g = (const float*)d_in[2];
  const float* ln_in_b = (const float*)d_in[3];
  const float* Wk = (const float*)d_in[4];
  const float* Wv = (const float*)d_in[5];
  const float* Wq = (const float*)d_in[6];
  const float* Wo = (const float*)d_in[7];
  const float* ln_s_g = (const float*)d_in[8];
  const float* ln_s_b = (const float*)d_in[9];
  const float* ln_f_g = (const float*)d_in[10];
  const float* ln_f_b = (const float*)d_in[11];
  const float* W1 = (const float*)d_in[12];
  const float* b1 = (const float*)d_in[13];
  const float* W2 = (const float*)d_in[14];
  const float* b2 = (const float*)d_in[15];
  float* out_slots = (float*)d_out;
  float* out_amean = (float*)d_out + (size_t)Bb*NSs*Dd;

  char* w = (char*)d_ws;
  auto alloc = [&](size_t bytes) {
    char* p = w; w += (bytes + 255) & ~(size_t)255; return p;
  };
  u16*  xn    = (u16*)alloc((size_t)Bb*Nn*Dd*2);
  u16*  kbuf  = (u16*)alloc((size_t)Bb*Nn*Dd*2);
  u16*  vT    = (u16*)alloc((size_t)Bb*Nn*Dd*2);   // [512][B*N]
  float* Tpart = (float*)alloc((size_t)JS*Bb*8*16*64*4);  // [js][b][h][i][d]
  float* slots = (float*)alloc((size_t)Bb*NSs*Dd*4);
  u16*  qb    = (u16*)alloc((size_t)Bb*NSs*Dd*2);
  u16*  snb   = (u16*)alloc((size_t)Bb*NSs*Dd*2);
  u16*  s2nb  = (u16*)alloc((size_t)Bb*NSs*Dd*2);
  u16*  h1b   = (u16*)alloc((size_t)Bb*NSs*DFF*2);
  u16*  updb  = (u16*)alloc((size_t)Bb*NSs*Dd*2);
  float* rowsum = (float*)alloc((size_t)Bb*128*3*4);   // one per iteration
  u16*  wkb = (u16*)alloc(262144*2);
  u16*  wvb = (u16*)alloc(262144*2);
  u16*  wqb = (u16*)alloc(262144*2);
  u16*  wob = (u16*)alloc(262144*2);
  u16*  w1t = (u16*)alloc((size_t)1048576*2);
  u16*  w2t = (u16*)alloc((size_t)1048576*2);

  // weights -> bf16 (W1/W2 transposed so B-operand is [out,K] row-major)
  cvt_w<<<1024, 256, 0, stream>>>(Wk, wkb, 262144);
  cvt_w<<<1024, 256, 0, stream>>>(Wv, wvb, 262144);
  cvt_w<<<1024, 256, 0, stream>>>(Wq, wqb, 262144);
  cvt_w<<<1024, 256, 0, stream>>>(Wo, wob, 262144);
  tr_cvt<<<dim3(64, 16), 256, 0, stream>>>(W1, w1t, 512, 2048);
  tr_cvt<<<dim3(16, 64), 256, 0, stream>>>(W2, w2t, 2048, 512);
  // slots <- conditioning; rowsum <- 0 (all 3 iterations)
  copy_f32v4<<<256, 256, 0, stream>>>(cond, slots, 65536);
  (void)hipMemsetAsync(rowsum, 0, (size_t)Bb*128*3*4, stream);
  // x = LN(inputs) -> bf16
  ln_rows<<<Bb*Nn/4, 256, 0, stream>>>(inputs, ln_in_g, ln_in_b, xn, Bb*Nn);
  // fused: k = x @ Wk^T  [B*N,512]  and  vT = (x @ Wv^T)^T  [512, B*N]
  gemm_kv<<<dim3(4, Bb*Nn/128), 256, 0, stream>>>(xn, wkb, wvb, kbuf, vT);

  for (int it = 0; it < 3; ++it) {
    float* rsp = rowsum + (size_t)it * Bb * 128;
    ln_rows<<<128, 256, 0, stream>>>(slots, ln_s_g, ln_s_b, snb, Bb*NSs);
    gemm64<0><<<dim3(8, 8), 256, 0, stream>>>(snb, wqb, qb, nullptr, nullptr, 512, 512);
    attn_f<<<dim3(JS, Bb), 512, 0, stream>>>(qb, kbuf, vT, rsp, Tpart,
                                             it == 2 ? out_amean : nullptr);
    upd_c<<<1024, 256, 0, stream>>>(Tpart, rsp, updb);
    gemm64<1><<<dim3(8, 8), 256, 0, stream>>>(updb, wob, slots, nullptr, slots, 512, 512);
    ln_rows<<<128, 256, 0, stream>>>(slots, ln_f_g, ln_f_b, s2nb, Bb*NSs);
    gemm64<2><<<dim3(32, 8), 256, 0, stream>>>(s2nb, w1t, h1b, b1, nullptr, 2048, 512);
    gemm64<3><<<dim3(8, 8), 256, 0, stream>>>(h1b, w2t, slots, b2, slots, 512, 2048);
  }
  copy_f32v4<<<256, 256, 0, stream>>>(slots, out_slots, 65536);
}